// Round 2
// baseline (1074.433 us; speedup 1.0000x reference)
//
#include <hip/hip_runtime.h>
#include <stdint.h>

// ---------------- problem constants ----------------
#define T_TOK   8192          // B*S
#define D_DIM   1024
#define FF_DIM  4096
#define E_NUM   8
#define SLOT_MAX 18432        // 16384 + 8*256 (worst-case 256-padded slots)
#define RT_MAX  104           // 72 moe row-tiles + 32 dense row-tiles (256-row tiles)

typedef unsigned int   u32;
typedef unsigned short u16;
typedef __attribute__((ext_vector_type(4))) float  f32x4;
typedef __attribute__((ext_vector_type(4))) float  f4;
typedef __attribute__((ext_vector_type(8))) short  bf16x8;   // 8 bf16 = 4 VGPR
typedef __attribute__((ext_vector_type(8))) unsigned short u16x8;

__device__ __forceinline__ u16 f2bf(float f) {              // RNE f32->bf16
  u32 u = __builtin_bit_cast(u32, f);
  return (u16)((u + 0x7fffu + ((u >> 16) & 1u)) >> 16);
}
__device__ __forceinline__ float bf2f(u16 h) {
  u32 u = ((u32)h) << 16; return __builtin_bit_cast(float, u);
}

typedef const __attribute__((address_space(1))) u32* gp1_t;
typedef __attribute__((address_space(3))) u32*       lp3_t;
__device__ __forceinline__ void gload16(const u16* g, u16* l) {
  // async global->LDS, 16B/lane, LDS dest = wave-uniform base + lane*16 (linear!)
  __builtin_amdgcn_global_load_lds((gp1_t)(const void*)g, (lp3_t)l, 16, 0, 0);
}
__device__ __forceinline__ bf16x8 ldsrd(const u16* base, int byteoff) {
  return *(const bf16x8*)((const char*)base + byteoff);
}

// ---------------- K0: zero header ----------------
__global__ void k_init(int* hdr) { if (threadIdx.x < 64) hdr[threadIdx.x] = 0; }

// ---------------- K1: router + gate (wave per token) ----------------
__global__ __launch_bounds__(256) void k_route(
    const float* __restrict__ x, const float* __restrict__ Wr, const float* __restrict__ br,
    const float* __restrict__ Wg, const float* __restrict__ bg,
    int* __restrict__ hdr, int4* __restrict__ tok_sel, float4* __restrict__ tok_wf)
{
  int w = threadIdx.x >> 6, l = threadIdx.x & 63;
  int t = blockIdx.x * 4 + w;
  const float* xt = x + (size_t)t * D_DIM;
  float p[10];
  #pragma unroll
  for (int i = 0; i < 10; ++i) p[i] = 0.f;
  for (int j = 0; j < D_DIM / 64; ++j) {
    int d = j * 64 + l;
    float xv = xt[d];
    p[0] += xv * Wr[d * 2 + 0];
    p[1] += xv * Wr[d * 2 + 1];
    f4 g0 = *(const f4*)&Wg[d * 8];
    f4 g1 = *(const f4*)&Wg[d * 8 + 4];
    p[2] += xv * g0[0]; p[3] += xv * g0[1]; p[4] += xv * g0[2]; p[5] += xv * g0[3];
    p[6] += xv * g1[0]; p[7] += xv * g1[1]; p[8] += xv * g1[2]; p[9] += xv * g1[3];
  }
  #pragma unroll
  for (int off = 32; off; off >>= 1) {
    #pragma unroll
    for (int i = 0; i < 10; ++i) p[i] += __shfl_xor(p[i], off, 64);
  }
  if (l == 0) {
    float a0 = p[0] + br[0], a1 = p[1] + br[1];
    float m  = fmaxf(a0, a1);
    float e0 = __expf(a0 - m), e1 = __expf(a1 - m);
    float rs = 1.f / (e0 + e1);
    float rp0 = e0 * rs, rp1 = e1 * rs;
    float g[E_NUM]; float gm = -1e30f;
    #pragma unroll
    for (int e = 0; e < E_NUM; ++e) { g[e] = p[2 + e] + bg[e]; gm = fmaxf(gm, g[e]); }
    int i0 = 0;
    #pragma unroll
    for (int e = 1; e < E_NUM; ++e) if (g[e] > g[i0]) i0 = e;      // earliest max tiebreak
    int i1 = (i0 == 0) ? 1 : 0;
    #pragma unroll
    for (int e = 0; e < E_NUM; ++e) if (e != i0 && g[e] > g[i1]) i1 = e;
    float x0 = __expf(g[i0] - gm), x1 = __expf(g[i1] - gm);
    float s = 1.f / (x0 + x1);
    int r0 = atomicAdd(&hdr[i0], 1);
    int r1 = atomicAdd(&hdr[i1], 1);
    tok_sel[t] = make_int4(i0, r0, i1, r1);
    tok_wf[t]  = make_float4(x0 * s, x1 * s, rp0, rp1);
  }
}

// ---------------- K2: padded offsets + tile map + perm=-1 ----------------
__global__ __launch_bounds__(256) void k_offsets(int* __restrict__ hdr,
                                                 int4* __restrict__ tilemap,
                                                 int* __restrict__ perm)
{
  __shared__ int soff[E_NUM + 1];
  int tid = threadIdx.x;
  if (tid == 0) {
    int acc = 0;
    for (int e = 0; e < E_NUM; ++e) {
      soff[e] = acc; hdr[8 + e] = acc;
      acc += (hdr[e] + 255) & ~255;                // pad each expert to 256
    }
    soff[E_NUM] = acc;
    hdr[16] = acc;                                 // nslots_padded
    hdr[17] = acc >> 8;                            // moe row-tiles (256-row)
    hdr[18] = (acc >> 8) + T_TOK / 256;            // total row-tiles
  }
  __syncthreads();
  int nmoe = soff[E_NUM] >> 8;
  for (int rt = tid; rt < RT_MAX; rt += 256) {
    int4 ent;
    if (rt < nmoe) {
      int row0 = rt * 256;
      int e = 0;
      while (e < E_NUM - 1 && row0 >= soff[e + 1]) ++e;
      ent = make_int4(0, row0, e, 0);
    } else if (rt < nmoe + T_TOK / 256) {
      ent = make_int4(1, (rt - nmoe) * 256, -1, 0);
    } else {
      ent = make_int4(-1, 0, 0, 0);
    }
    tilemap[rt] = ent;
  }
  for (int s = tid; s < SLOT_MAX; s += 256) perm[s] = -1;
}

// ---------------- K3: scatter token -> slots ----------------
__global__ void k_scatter(const int4* __restrict__ tok_sel, const int* __restrict__ hdr,
                          int* __restrict__ perm, int2* __restrict__ tok_slot)
{
  int t = blockIdx.x * 256 + threadIdx.x;
  if (t >= T_TOK) return;
  int4 s = tok_sel[t];
  int s0 = hdr[8 + s.x] + s.y;
  int s1 = hdr[8 + s.z] + s.w;
  perm[s0] = t; perm[s1] = t;
  tok_slot[t] = make_int2(s0, s1);
}

// ---------------- K4: cast x -> bf16 ----------------
__global__ void k_cast(const float* __restrict__ x, u16* __restrict__ xb, int n8) {
  int i = blockIdx.x * 256 + threadIdx.x;
  if (i >= n8) return;
  const f4* src = (const f4*)x + (size_t)i * 2;
  f4 a = src[0], b = src[1];
  u16x8 o;
  o[0]=f2bf(a[0]); o[1]=f2bf(a[1]); o[2]=f2bf(a[2]); o[3]=f2bf(a[3]);
  o[4]=f2bf(b[0]); o[5]=f2bf(b[1]); o[6]=f2bf(b[2]); o[7]=f2bf(b[3]);
  ((u16x8*)xb)[i] = o;
}

// ---------------- K5: gather x rows into slot order ----------------
__global__ __launch_bounds__(256) void k_gather(const u16* __restrict__ xb,
                                                const int* __restrict__ perm,
                                                const int* __restrict__ hdr,
                                                u16* __restrict__ xg)
{
  int nslots = hdr[16];
  int row = blockIdx.x * 2 + (threadIdx.x >> 7);
  if (row >= nslots) return;
  int lane = threadIdx.x & 127;
  int t = perm[row];
  u16x8* dst = (u16x8*)(xg + (size_t)row * D_DIM) + lane;
  if (t < 0) { u16x8 z = {0,0,0,0,0,0,0,0}; *dst = z; }
  else       { *dst = *((const u16x8*)(xb + (size_t)t * D_DIM) + lane); }
}

// ---------------- K6: cast+transpose f32 [R,C] -> bf16 [C,R] ----------------
__global__ __launch_bounds__(256) void k_tcast(const float* __restrict__ src,
                                               u16* __restrict__ dst, int R, int C)
{
  const float* s = src + (size_t)blockIdx.z * R * C;
  u16* d = dst + (size_t)blockIdx.z * R * C;
  __shared__ float tile[64][65];
  int tr = blockIdx.y, tc = blockIdx.x;
  int t = threadIdx.x;
  #pragma unroll
  for (int p = 0; p < 4; ++p) {
    int r = p * 16 + (t >> 4);
    int c4 = (t & 15) * 4;
    f4 v = *(const f4*)&s[(size_t)(tr * 64 + r) * C + tc * 64 + c4];
    tile[r][c4+0] = v[0]; tile[r][c4+1] = v[1]; tile[r][c4+2] = v[2]; tile[r][c4+3] = v[3];
  }
  __syncthreads();
  #pragma unroll
  for (int q = 0; q < 2; ++q) {
    int oc = q * 32 + (t >> 3);
    int r8 = (t & 7) * 8;
    u16x8 o;
    #pragma unroll
    for (int j = 0; j < 8; ++j) o[j] = f2bf(tile[r8 + j][oc]);
    *(u16x8*)&d[(size_t)(tc * 64 + oc) * R + tr * 64 + r8] = o;
  }
}

// ---------------- K7/K8: grouped GEMM, 256x256 8-phase structure ----------------
// BM=BN=256, BK=64, 8 waves (2M x 4N), per-wave 128x64 output (acc[8][4] f32x4).
// LDS: 2 x (A 32KB + B 32KB) = 128KB double buffer, LINEAR layout (global_load_lds),
// frag reads use G4 XOR swizzle byte^=(row&7)<<4 realized via pre-swizzled SOURCE
// addresses (rule #21: both-sides-or-neither; XOR on bits 4-6 is an involution).
// Sync: per-tile {barrier; STAGE(t+2,same buf); vmcnt(8); barrier} -- vmcnt retires
// in order, so <=8 outstanding means tile t+1's 8 loads have landed. Never 0 in loop.
#define READA(mh_) { _Pragma("unroll") for (int mi = 0; mi < 4; ++mi) { \
    aF[mi][0] = ldsrd(Ab, aOff0 + ((mh_)*4 + mi) * 2048); \
    aF[mi][1] = ldsrd(Ab, aOff1 + ((mh_)*4 + mi) * 2048); } }
#define READB(nh_) { _Pragma("unroll") for (int ni = 0; ni < 2; ++ni) { \
    bF[(nh_)*2+ni][0] = ldsrd(Bb, bOff0 + ((nh_)*2 + ni) * 2048); \
    bF[(nh_)*2+ni][1] = ldsrd(Bb, bOff1 + ((nh_)*2 + ni) * 2048); } }
#define MFMA16(mh_, nh_) { _Pragma("unroll") for (int mi = 0; mi < 4; ++mi) { \
    _Pragma("unroll") for (int ni = 0; ni < 2; ++ni) { \
      acc[(mh_)*4+mi][(nh_)*2+ni] = __builtin_amdgcn_mfma_f32_16x16x32_bf16(aF[mi][0], bF[(nh_)*2+ni][0], acc[(mh_)*4+mi][(nh_)*2+ni], 0, 0, 0); \
      acc[(mh_)*4+mi][(nh_)*2+ni] = __builtin_amdgcn_mfma_f32_16x16x32_bf16(aF[mi][1], bF[(nh_)*2+ni][1], acc[(mh_)*4+mi][(nh_)*2+ni], 0, 0, 0); } } }
#define STAGE(t2_, bb_) { size_t ko_ = (size_t)(t2_) * 64; \
    _Pragma("unroll") for (int j = 0; j < 4; ++j) { \
      gload16(aS + ko_ + (size_t)j * 64 * K, &sA[bb_][j * 4096 + wid * 512]); \
      gload16(bS + ko_ + (size_t)j * 64 * K, &sB[bb_][j * 4096 + wid * 512]); } }

template <int RELU>
__global__ __launch_bounds__(512, 2) void k_gemm8(
    const u16* __restrict__ Amoe, const u16* __restrict__ Aden,
    const u16* __restrict__ Bexp, const u16* __restrict__ Bden,
    const float* __restrict__ biasexp, const float* __restrict__ biasden,
    u16* __restrict__ Omoe, u16* __restrict__ Oden,
    const int* __restrict__ hdr, const int4* __restrict__ tilemap,
    int K, int N, long bexp_stride, int biasexp_stride, int lg2gx)
{
  // bijective XCD-aware swizzle (nwg % 8 == 0 for both GEMMs)
  int gx  = 1 << lg2gx;
  int nwg = gx * gridDim.y;
  int lin = blockIdx.y * gx + blockIdx.x;
  int s   = (lin & 7) * (nwg >> 3) + (lin >> 3);
  int ct  = s & (gx - 1);
  int rt  = s >> lg2gx;
  if (rt >= hdr[18]) return;

  int4 ent = tilemap[rt];
  const u16* A; const u16* B; const float* bias; u16* O;
  if (ent.x == 1) { A = Aden; B = Bden; bias = biasden; O = Oden; }
  else {
    A = Amoe; B = Bexp + (size_t)ent.z * bexp_stride;
    bias = biasexp + (size_t)ent.z * biasexp_stride; O = Omoe;
  }
  const int row0 = ent.y;

  __shared__ __align__(16) u16 sA[2][256 * 64];   // 2 x 32KB
  __shared__ __align__(16) u16 sB[2][256 * 64];   // 2 x 32KB

  const int tid = threadIdx.x;
  const int wid = tid >> 6, l = tid & 63;
  const int wm = wid >> 2, wn = wid & 3;

  // --- staging source (pre-swizzled global address; LDS dest stays linear) ---
  // linear LDS byte L = j*8192 + wid*1024 + lane*16  ->  row = L>>7, kbyte = L&127
  // want LDS[row][kbyte] = global[row][kbyte ^ ((row&7)<<4)] ; row&7 == lane>>3
  const int srow = wid * 8 + (l >> 3);                  // + j*64
  const int skel = ((l & 7) ^ (l >> 3)) * 8;            // swizzled k-element in [0,64)
  const u16* aS = A + (size_t)(row0    + srow) * K + skel;
  const u16* bS = B + (size_t)(ct * 256 + srow) * K + skel;

  // --- fragment-read byte offsets (apply the same XOR on the read side) ---
  const int fr = l & 15;            // frag row
  const int fq = l >> 4;            // 0..3
  const int fx = (l & 7) << 4;      // XOR term: row&7 == l&7 for all frag rows
  const int aOff0 = (wm * 128 + fr) * 128 + ((fq * 16)      ^ fx);
  const int aOff1 = (wm * 128 + fr) * 128 + ((fq * 16 + 64) ^ fx);
  const int bOff0 = (wn * 64  + fr) * 128 + ((fq * 16)      ^ fx);
  const int bOff1 = (wn * 64  + fr) * 128 + ((fq * 16 + 64) ^ fx);

  f32x4 acc[8][4];
  #pragma unroll
  for (int m = 0; m < 8; ++m)
    #pragma unroll
    for (int n = 0; n < 4; ++n) acc[m][n] = (f32x4){0.f, 0.f, 0.f, 0.f};

  bf16x8 aF[4][2], bF[4][2];
  const int NK = K >> 6;

  // prologue: stage tiles 0,1; wait tile 0 (8 of 16 outstanding may remain)
  STAGE(0, 0);
  STAGE(1, 1);
  asm volatile("s_waitcnt vmcnt(8)" ::: "memory");
  __builtin_amdgcn_s_barrier();

  for (int t = 0; t < NK; ++t) {
    const u16* Ab = sA[t & 1];
    const u16* Bb = sB[t & 1];
    // phase 1: quadrant (mh0, nh0)
    READA(0); READB(0);
    __builtin_amdgcn_s_barrier();
    asm volatile("s_waitcnt lgkmcnt(0)" ::: "memory");
    __builtin_amdgcn_sched_barrier(0);
    __builtin_amdgcn_s_setprio(1); MFMA16(0, 0); __builtin_amdgcn_s_setprio(0);
    __builtin_amdgcn_s_barrier();
    // phase 2: (mh0, nh1)
    READB(1);
    __builtin_amdgcn_s_barrier();
    asm volatile("s_waitcnt lgkmcnt(0)" ::: "memory");
    __builtin_amdgcn_sched_barrier(0);
    __builtin_amdgcn_s_setprio(1); MFMA16(0, 1); __builtin_amdgcn_s_setprio(0);
    __builtin_amdgcn_s_barrier();
    // phase 3: (mh1, nh0) -- reuses bF[0..1]
    READA(1);
    __builtin_amdgcn_s_barrier();
    asm volatile("s_waitcnt lgkmcnt(0)" ::: "memory");
    __builtin_amdgcn_sched_barrier(0);
    __builtin_amdgcn_s_setprio(1); MFMA16(1, 0); __builtin_amdgcn_s_setprio(0);
    __builtin_amdgcn_s_barrier();
    // phase 4: (mh1, nh1) -- no new reads
    __builtin_amdgcn_s_setprio(1); MFMA16(1, 1); __builtin_amdgcn_s_setprio(0);
    __builtin_amdgcn_s_barrier();          // all waves done reading buf (t&1)
    __builtin_amdgcn_sched_barrier(0);
    if (t + 2 < NK) {
      STAGE(t + 2, t & 1);                 // overwrite just-consumed buffer
      asm volatile("s_waitcnt vmcnt(8)" ::: "memory");   // tile t+1 landed
      __builtin_amdgcn_s_barrier();
    } else if (t + 1 < NK) {
      asm volatile("s_waitcnt vmcnt(0)" ::: "memory");   // tail only
      __builtin_amdgcn_s_barrier();
    }
  }

  // epilogue: C/D layout col=lane&15, row=(lane>>4)*4+reg (measured m89/m91)
  #pragma unroll
  for (int n = 0; n < 4; ++n) {
    int c = ct * 256 + wn * 64 + n * 16 + fr;
    float bv = bias[c];
    #pragma unroll
    for (int m = 0; m < 8; ++m) {
      int rbase = row0 + wm * 128 + m * 16 + fq * 4;
      f32x4 v = acc[m][n];
      #pragma unroll
      for (int j = 0; j < 4; ++j) {
        float f = v[j] + bv;
        if (RELU) f = fmaxf(f, 0.f);
        O[(size_t)(rbase + j) * N + c] = f2bf(f);
      }
    }
  }
}

// ---------------- K9: combine ----------------
__global__ __launch_bounds__(128) void k_combine(
    const u16* __restrict__ eo, const u16* __restrict__ dense_o,
    const float4* __restrict__ tok_wf, const int2* __restrict__ tok_slot,
    float* __restrict__ out)
{
  int t = blockIdx.x;
  int c8 = threadIdx.x;
  float4 wf = tok_wf[t];
  int2 sl = tok_slot[t];
  u16x8 a  = *((const u16x8*)(eo + (size_t)sl.x * D_DIM) + c8);
  u16x8 b  = *((const u16x8*)(eo + (size_t)sl.y * D_DIM) + c8);
  u16x8 dn = *((const u16x8*)(dense_o + (size_t)t * D_DIM) + c8);
  float* op = out + (size_t)t * D_DIM + c8 * 8;
  #pragma unroll
  for (int j = 0; j < 8; ++j) {
    float mo = wf.x * bf2f(a[j]) + wf.y * bf2f(b[j]);
    op[j] = wf.z * mo + wf.w * bf2f(dn[j]);
  }
}

// ---------------- launch ----------------
extern "C" void kernel_launch(void* const* d_in, const int* in_sizes, int n_in,
                              void* d_out, int out_size, void* d_ws, size_t ws_size,
                              hipStream_t stream)
{
  const float* x   = (const float*)d_in[0];
  const float* Wr  = (const float*)d_in[1];
  const float* br  = (const float*)d_in[2];
  const float* Wg  = (const float*)d_in[3];
  const float* bg  = (const float*)d_in[4];
  const float* W1  = (const float*)d_in[5];
  const float* b1  = (const float*)d_in[6];
  const float* W2  = (const float*)d_in[7];
  const float* b2  = (const float*)d_in[8];
  const float* D1  = (const float*)d_in[9];
  const float* d1b = (const float*)d_in[10];
  const float* D2  = (const float*)d_in[11];
  const float* d2b = (const float*)d_in[12];
  float* out = (float*)d_out;

  char* base = (char*)d_ws;
  size_t cur = 0;
  auto alloc = [&](size_t b) -> void* {
    void* p = base + cur; cur = (cur + b + 255) & ~(size_t)255; return p;
  };
  int*    hdr      = (int*)   alloc(256 * sizeof(int));
  int4*   tilemap  = (int4*)  alloc((size_t)RT_MAX * sizeof(int4));
  int4*   tok_sel  = (int4*)  alloc((size_t)T_TOK * sizeof(int4));
  float4* tok_wf   = (float4*)alloc((size_t)T_TOK * sizeof(float4));
  int2*   tok_slot = (int2*)  alloc((size_t)T_TOK * sizeof(int2));
  int*    perm     = (int*)   alloc((size_t)SLOT_MAX * sizeof(int));
  u16*    xb       = (u16*)   alloc((size_t)T_TOK * D_DIM * 2);
  u16*    xg       = (u16*)   alloc((size_t)SLOT_MAX * D_DIM * 2);
  u16*    W1bt     = (u16*)   alloc((size_t)E_NUM * D_DIM * FF_DIM * 2);
  u16*    W2bt     = (u16*)   alloc((size_t)E_NUM * D_DIM * FF_DIM * 2);
  u16*    D1bt     = (u16*)   alloc((size_t)D_DIM * FF_DIM * 2);
  u16*    D2bt     = (u16*)   alloc((size_t)D_DIM * FF_DIM * 2);
  u16*    h_moe    = (u16*)   alloc((size_t)SLOT_MAX * FF_DIM * 2);
  u16*    h_dense  = (u16*)   alloc((size_t)T_TOK * FF_DIM * 2);
  u16*    eo       = (u16*)   alloc((size_t)SLOT_MAX * D_DIM * 2);
  u16*    dense_o  = (u16*)   alloc((size_t)T_TOK * D_DIM * 2);
  (void)in_sizes; (void)n_in; (void)out_size; (void)ws_size; // needs ~475 MB of ws

  k_init   <<<1, 64, 0, stream>>>(hdr);
  k_route  <<<T_TOK / 4, 256, 0, stream>>>(x, Wr, br, Wg, bg, hdr, tok_sel, tok_wf);
  k_offsets<<<1, 256, 0, stream>>>(hdr, tilemap, perm);
  k_scatter<<<T_TOK / 256, 256, 0, stream>>>(tok_sel, hdr, perm, tok_slot);
  k_cast   <<<(T_TOK * D_DIM / 8) / 256, 256, 0, stream>>>(x, xb, T_TOK * D_DIM / 8);
  k_gather <<<SLOT_MAX / 2, 256, 0, stream>>>(xb, perm, hdr, xg);
  k_tcast  <<<dim3(FF_DIM / 64, D_DIM / 64, E_NUM), 256, 0, stream>>>(W1, W1bt, D_DIM, FF_DIM);
  k_tcast  <<<dim3(D_DIM / 64, FF_DIM / 64, E_NUM), 256, 0, stream>>>(W2, W2bt, FF_DIM, D_DIM);
  k_tcast  <<<dim3(FF_DIM / 64, D_DIM / 64, 1), 256, 0, stream>>>(D1, D1bt, D_DIM, FF_DIM);
  k_tcast  <<<dim3(D_DIM / 64, FF_DIM / 64, 1), 256, 0, stream>>>(D2, D2bt, FF_DIM, D_DIM);

  // GEMM1: [slots|tokens] x W1 -> relu -> h   (N=4096, K=1024, gx=16)
  k_gemm8<1><<<dim3(FF_DIM / 256, RT_MAX), 512, 0, stream>>>(
      xg, xb, W1bt, D1bt, b1, d1b, h_moe, h_dense, hdr, tilemap,
      D_DIM, FF_DIM, (long)D_DIM * FF_DIM, FF_DIM, 4);
  // GEMM2: h x W2 -> eo  (N=1024, K=4096, gx=4)
  k_gemm8<0><<<dim3(D_DIM / 256, RT_MAX), 512, 0, stream>>>(
      h_moe, h_dense, W2bt, D2bt, b2, d2b, eo, dense_o, hdr, tilemap,
      FF_DIM, D_DIM, (long)D_DIM * FF_DIM, D_DIM, 2);

  k_combine<<<T_TOK, 128, 0, stream>>>(eo, dense_o, tok_wf, tok_slot, out);
}

// Round 3
// 1015.172 us; speedup vs baseline: 1.0584x; 1.0584x over previous
//
#include <hip/hip_runtime.h>
#include <stdint.h>

// ---------------- problem constants ----------------
#define T_TOK   8192          // B*S
#define D_DIM   1024
#define FF_DIM  4096
#define E_NUM   8
#define SLOT_MAX 18432        // 16384 + 8*256 (worst-case 256-padded slots)
#define RT_MAX  104           // 72 moe row-tiles + 32 dense row-tiles (256-row tiles)

typedef unsigned int   u32;
typedef unsigned short u16;
typedef __attribute__((ext_vector_type(4))) float  f32x4;
typedef __attribute__((ext_vector_type(4))) float  f4;
typedef __attribute__((ext_vector_type(8))) short  bf16x8;   // 8 bf16 = 4 VGPR
typedef __attribute__((ext_vector_type(8))) unsigned short u16x8;

__device__ __forceinline__ u16 f2bf(float f) {              // RNE f32->bf16
  u32 u = __builtin_bit_cast(u32, f);
  return (u16)((u + 0x7fffu + ((u >> 16) & 1u)) >> 16);
}
__device__ __forceinline__ float bf2f(u16 h) {
  u32 u = ((u32)h) << 16; return __builtin_bit_cast(float, u);
}

typedef const __attribute__((address_space(1))) u32* gp1_t;
typedef __attribute__((address_space(3))) u32*       lp3_t;
__device__ __forceinline__ void gload16(const u16* g, u16* l) {
  // async global->LDS, 16B/lane, LDS dest = wave-uniform base + lane*16 (linear)
  __builtin_amdgcn_global_load_lds((gp1_t)(const void*)g, (lp3_t)l, 16, 0, 0);
}

template <int N> __device__ __forceinline__ void vmwait() {
  if constexpr (N == 8)      asm volatile("s_waitcnt vmcnt(8)" ::: "memory");
  else if constexpr (N == 6) asm volatile("s_waitcnt vmcnt(6)" ::: "memory");
  else if constexpr (N == 4) asm volatile("s_waitcnt vmcnt(4)" ::: "memory");
  else if constexpr (N == 3) asm volatile("s_waitcnt vmcnt(3)" ::: "memory");
  else                       asm volatile("s_waitcnt vmcnt(0)" ::: "memory");
}

// ---------------- K0: zero header ----------------
__global__ void k_init(int* hdr) { if (threadIdx.x < 64) hdr[threadIdx.x] = 0; }

// ---------------- K1: router + gate (wave per token) ----------------
__global__ __launch_bounds__(256) void k_route(
    const float* __restrict__ x, const float* __restrict__ Wr, const float* __restrict__ br,
    const float* __restrict__ Wg, const float* __restrict__ bg,
    int* __restrict__ hdr, int4* __restrict__ tok_sel, float4* __restrict__ tok_wf)
{
  int w = threadIdx.x >> 6, l = threadIdx.x & 63;
  int t = blockIdx.x * 4 + w;
  const float* xt = x + (size_t)t * D_DIM;
  float p[10];
  #pragma unroll
  for (int i = 0; i < 10; ++i) p[i] = 0.f;
  for (int j = 0; j < D_DIM / 64; ++j) {
    int d = j * 64 + l;
    float xv = xt[d];
    p[0] += xv * Wr[d * 2 + 0];
    p[1] += xv * Wr[d * 2 + 1];
    f4 g0 = *(const f4*)&Wg[d * 8];
    f4 g1 = *(const f4*)&Wg[d * 8 + 4];
    p[2] += xv * g0[0]; p[3] += xv * g0[1]; p[4] += xv * g0[2]; p[5] += xv * g0[3];
    p[6] += xv * g1[0]; p[7] += xv * g1[1]; p[8] += xv * g1[2]; p[9] += xv * g1[3];
  }
  #pragma unroll
  for (int off = 32; off; off >>= 1) {
    #pragma unroll
    for (int i = 0; i < 10; ++i) p[i] += __shfl_xor(p[i], off, 64);
  }
  if (l == 0) {
    float a0 = p[0] + br[0], a1 = p[1] + br[1];
    float m  = fmaxf(a0, a1);
    float e0 = __expf(a0 - m), e1 = __expf(a1 - m);
    float rs = 1.f / (e0 + e1);
    float rp0 = e0 * rs, rp1 = e1 * rs;
    float g[E_NUM]; float gm = -1e30f;
    #pragma unroll
    for (int e = 0; e < E_NUM; ++e) { g[e] = p[2 + e] + bg[e]; gm = fmaxf(gm, g[e]); }
    int i0 = 0;
    #pragma unroll
    for (int e = 1; e < E_NUM; ++e) if (g[e] > g[i0]) i0 = e;      // earliest max tiebreak
    int i1 = (i0 == 0) ? 1 : 0;
    #pragma unroll
    for (int e = 0; e < E_NUM; ++e) if (e != i0 && g[e] > g[i1]) i1 = e;
    float x0 = __expf(g[i0] - gm), x1 = __expf(g[i1] - gm);
    float s = 1.f / (x0 + x1);
    int r0 = atomicAdd(&hdr[i0], 1);
    int r1 = atomicAdd(&hdr[i1], 1);
    tok_sel[t] = make_int4(i0, r0, i1, r1);
    tok_wf[t]  = make_float4(x0 * s, x1 * s, rp0, rp1);
  }
}

// ---------------- K2: padded offsets + tile map + perm=-1 ----------------
__global__ __launch_bounds__(256) void k_offsets(int* __restrict__ hdr,
                                                 int4* __restrict__ tilemap,
                                                 int* __restrict__ perm)
{
  __shared__ int soff[E_NUM + 1];
  int tid = threadIdx.x;
  if (tid == 0) {
    int acc = 0;
    for (int e = 0; e < E_NUM; ++e) {
      soff[e] = acc; hdr[8 + e] = acc;
      acc += (hdr[e] + 255) & ~255;                // pad each expert to 256
    }
    soff[E_NUM] = acc;
    hdr[16] = acc;                                 // nslots_padded
    hdr[17] = acc >> 8;                            // moe row-tiles (256-row)
    hdr[18] = (acc >> 8) + T_TOK / 256;            // total row-tiles
  }
  __syncthreads();
  int nmoe = soff[E_NUM] >> 8;
  for (int rt = tid; rt < RT_MAX; rt += 256) {
    int4 ent;
    if (rt < nmoe) {
      int row0 = rt * 256;
      int e = 0;
      while (e < E_NUM - 1 && row0 >= soff[e + 1]) ++e;
      ent = make_int4(0, row0, e, 0);
    } else if (rt < nmoe + T_TOK / 256) {
      ent = make_int4(1, (rt - nmoe) * 256, -1, 0);
    } else {
      ent = make_int4(-1, 0, 0, 0);
    }
    tilemap[rt] = ent;
  }
  for (int s = tid; s < SLOT_MAX; s += 256) perm[s] = -1;
}

// ---------------- K3: scatter token -> slots ----------------
__global__ void k_scatter(const int4* __restrict__ tok_sel, const int* __restrict__ hdr,
                          int* __restrict__ perm, int2* __restrict__ tok_slot)
{
  int t = blockIdx.x * 256 + threadIdx.x;
  if (t >= T_TOK) return;
  int4 s = tok_sel[t];
  int s0 = hdr[8 + s.x] + s.y;
  int s1 = hdr[8 + s.z] + s.w;
  perm[s0] = t; perm[s1] = t;
  tok_slot[t] = make_int2(s0, s1);
}

// ---------------- K4: cast x -> bf16 ----------------
__global__ void k_cast(const float* __restrict__ x, u16* __restrict__ xb, int n8) {
  int i = blockIdx.x * 256 + threadIdx.x;
  if (i >= n8) return;
  const f4* src = (const f4*)x + (size_t)i * 2;
  f4 a = src[0], b = src[1];
  u16x8 o;
  o[0]=f2bf(a[0]); o[1]=f2bf(a[1]); o[2]=f2bf(a[2]); o[3]=f2bf(a[3]);
  o[4]=f2bf(b[0]); o[5]=f2bf(b[1]); o[6]=f2bf(b[2]); o[7]=f2bf(b[3]);
  ((u16x8*)xb)[i] = o;
}

// ---------------- K5: gather x rows into slot order ----------------
__global__ __launch_bounds__(256) void k_gather(const u16* __restrict__ xb,
                                                const int* __restrict__ perm,
                                                const int* __restrict__ hdr,
                                                u16* __restrict__ xg)
{
  int nslots = hdr[16];
  int row = blockIdx.x * 2 + (threadIdx.x >> 7);
  if (row >= nslots) return;
  int lane = threadIdx.x & 127;
  int t = perm[row];
  u16x8* dst = (u16x8*)(xg + (size_t)row * D_DIM) + lane;
  if (t < 0) { u16x8 z = {0,0,0,0,0,0,0,0}; *dst = z; }
  else       { *dst = *((const u16x8*)(xb + (size_t)t * D_DIM) + lane); }
}

// ---------------- K6: cast+transpose f32 [R,C] -> bf16 [C,R] ----------------
__global__ __launch_bounds__(256) void k_tcast(const float* __restrict__ src,
                                               u16* __restrict__ dst, int R, int C)
{
  const float* s = src + (size_t)blockIdx.z * R * C;
  u16* d = dst + (size_t)blockIdx.z * R * C;
  __shared__ float tile[64][65];
  int tr = blockIdx.y, tc = blockIdx.x;
  int t = threadIdx.x;
  #pragma unroll
  for (int p = 0; p < 4; ++p) {
    int r = p * 16 + (t >> 4);
    int c4 = (t & 15) * 4;
    f4 v = *(const f4*)&s[(size_t)(tr * 64 + r) * C + tc * 64 + c4];
    tile[r][c4+0] = v[0]; tile[r][c4+1] = v[1]; tile[r][c4+2] = v[2]; tile[r][c4+3] = v[3];
  }
  __syncthreads();
  #pragma unroll
  for (int q = 0; q < 2; ++q) {
    int oc = q * 32 + (t >> 3);
    int r8 = (t & 7) * 8;
    u16x8 o;
    #pragma unroll
    for (int j = 0; j < 8; ++j) o[j] = f2bf(tile[r8 + j][oc]);
    *(u16x8*)&d[(size_t)(tc * 64 + oc) * R + tr * 64 + r8] = o;
  }
}

// ---------------- K7/K8: grouped GEMM, 256xBN ring-buffer free-run ----------------
// BM=256, BK=32, 8 waves. LDS = 4-deep ring of (A 16KB + B BN*64B), 16-row dense
// blocks: LDS[blk][fq][fr][8 elems] so every frag ds_read_b128 is a dense 1KB wave
// read (conflict-free, no swizzle, linear gload_lds dest). Per K-tile: stage tile
// t+3 (ring), plain ds_reads + MFMAs (compiler emits fine-grained lgkmcnt), then
// ONE counted vmcnt (never 0 in steady state) + ONE raw s_barrier. Waves free-run
// within a tile -> cross-wave MFMA/DS overlap instead of r2's lockstep phases.
template <int BN, int RELU>
__global__ __launch_bounds__(512, 2) void k_gemm_ring(
    const u16* __restrict__ Amoe, const u16* __restrict__ Aden,
    const u16* __restrict__ Bexp, const u16* __restrict__ Bden,
    const float* __restrict__ biasexp, const float* __restrict__ biasden,
    u16* __restrict__ Omoe, u16* __restrict__ Oden,
    const int* __restrict__ hdr, const int4* __restrict__ tilemap,
    int K, int N, long bexp_stride, int biasexp_stride, int lg2gx)
{
  constexpr int MF  = (BN == 256) ? 8 : 4;     // A-frags per wave
  constexpr int L   = (BN == 256) ? 4 : 3;     // gloads per thread per tile
  constexpr int TBu = 8192 + BN * 32;          // ring slot size in u16
  constexpr int WROWS = (BN == 256) ? 128 : 64;

  // bijective XCD-aware swizzle (nwg % 8 == 0 for both launches)
  int gx  = 1 << lg2gx;
  int nwg = gx * gridDim.y;
  int lin = blockIdx.y * gx + blockIdx.x;
  int sw  = (lin & 7) * (nwg >> 3) + (lin >> 3);
  int ct  = sw & (gx - 1);
  int rt  = sw >> lg2gx;
  if (rt >= hdr[18]) return;

  int4 ent = tilemap[rt];
  const u16* A; const u16* B; const float* bias; u16* O;
  if (ent.x == 1) { A = Aden; B = Bden; bias = biasden; O = Oden; }
  else {
    A = Amoe; B = Bexp + (size_t)ent.z * bexp_stride;
    bias = biasexp + (size_t)ent.z * biasexp_stride;
    O = Omoe;
  }
  const int row0 = ent.y;

  __shared__ __align__(16) u16 lds[4 * TBu];

  const int tid = threadIdx.x;
  const int wid = tid >> 6, l = tid & 63;
  const int wm = (BN == 256) ? (wid >> 2) : (wid >> 1);
  const int wn = (BN == 256) ? (wid & 3) : (wid & 1);

  // staging source: wave stages 16-row dense blocks; lane l -> row (l&15), k (l>>4)*8
  const int sr = l & 15, sk = (l >> 4) * 8;
  const u16* aSrc0 = A + (size_t)(row0 + wid * 16 + sr) * K + sk;
  const u16* aSrc1 = aSrc0 + (size_t)128 * K;
  const u16* bSrc0 = B + (size_t)(ct * BN + wid * 16 + sr) * K + sk;
  const u16* bSrc1 = bSrc0 + (size_t)128 * K;        // only used when BN==256

  // frag-read offsets (u16 units): blk*512 + fq*128 + fr*8
  const int fr = l & 15, fq = l >> 4;
  const int aOffU = wm * MF * 512 + fq * 128 + fr * 8;
  const int bOffU = 8192 + wn * 4 * 512 + fq * 128 + fr * 8;

  float bv[4];
  #pragma unroll
  for (int ni = 0; ni < 4; ++ni) bv[ni] = bias[ct * BN + wn * 64 + ni * 16 + fr];

  f32x4 acc[MF][4];
  #pragma unroll
  for (int m = 0; m < MF; ++m)
    #pragma unroll
    for (int n = 0; n < 4; ++n) acc[m][n] = (f32x4){0.f, 0.f, 0.f, 0.f};

  const int NK = K >> 5;

  auto STAGE = [&](int tt) {
    const size_t ko = (size_t)tt * 32;
    u16* dst = &lds[(tt & 3) * TBu];
    gload16(aSrc0 + ko, dst + wid * 512);
    gload16(aSrc1 + ko, dst + 4096 + wid * 512);
    gload16(bSrc0 + ko, dst + 8192 + wid * 512);
    if constexpr (BN == 256) gload16(bSrc1 + ko, dst + 8192 + 4096 + wid * 512);
  };

  // prologue: 3-deep prefetch (NK >= 4 always: 32 or 128)
  STAGE(0); STAGE(1); STAGE(2);
  vmwait<2 * L>();                     // tile 0 landed; 1,2 in flight
  __builtin_amdgcn_s_barrier();
  __builtin_amdgcn_sched_barrier(0);

  for (int t = 0; t < NK; ++t) {
    if (t + 3 < NK) STAGE(t + 3);
    const u16* Tb = &lds[(t & 3) * TBu];
    bf16x8 aF[MF], bF[4];
    #pragma unroll
    for (int ni = 0; ni < 4; ++ni) bF[ni] = *(const bf16x8*)&Tb[bOffU + ni * 512];
    #pragma unroll
    for (int mi = 0; mi < MF; ++mi) aF[mi] = *(const bf16x8*)&Tb[aOffU + mi * 512];
    #pragma unroll
    for (int mi = 0; mi < MF; ++mi)
      #pragma unroll
      for (int ni = 0; ni < 4; ++ni)
        acc[mi][ni] = __builtin_amdgcn_mfma_f32_16x16x32_bf16(aF[mi], bF[ni], acc[mi][ni], 0, 0, 0);
    if (t + 1 < NK) {
      if (t + 3 < NK)      vmwait<2 * L>();   // allow tiles t+2,t+3 in flight
      else if (t + 2 < NK) vmwait<L>();       // allow t+2
      else                 vmwait<0>();
      __builtin_amdgcn_s_barrier();
      __builtin_amdgcn_sched_barrier(0);
    }
  }

  // ---- epilogue: per-wave LDS-bounce transpose -> coalesced u16x8 stores ----
  __syncthreads();                       // full drain once; LDS reused as scratch
  float* ep = (float*)((char*)lds + wid * 4096);
  const int row16 = l >> 2, cg = l & 3;
  #pragma unroll
  for (int mi = 0; mi < MF; ++mi) {
    #pragma unroll
    for (int ni = 0; ni < 4; ++ni) {
      f32x4 v = acc[mi][ni];
      #pragma unroll
      for (int j = 0; j < 4; ++j) {
        float f = v[j] + bv[ni];
        if (RELU) f = fmaxf(f, 0.f);
        ep[(fq * 4 + j) * 64 + ni * 16 + fr] = f;   // wave-private 4KB
      }
    }
    #pragma unroll
    for (int p = 0; p < 2; ++p) {
      f4 r0 = *(f4*)&ep[row16 * 64 + (cg + p * 4) * 8];
      f4 r1 = *(f4*)&ep[row16 * 64 + (cg + p * 4) * 8 + 4];
      u16x8 o;
      o[0]=f2bf(r0[0]); o[1]=f2bf(r0[1]); o[2]=f2bf(r0[2]); o[3]=f2bf(r0[3]);
      o[4]=f2bf(r1[0]); o[5]=f2bf(r1[1]); o[6]=f2bf(r1[2]); o[7]=f2bf(r1[3]);
      int rr = row0 + wm * WROWS + mi * 16 + row16;
      int cc = ct * BN + wn * 64 + (cg + p * 4) * 8;
      *(u16x8*)&O[(size_t)rr * N + cc] = o;
    }
  }
}

// ---------------- K9: combine ----------------
__global__ __launch_bounds__(128) void k_combine(
    const u16* __restrict__ eo, const u16* __restrict__ dense_o,
    const float4* __restrict__ tok_wf, const int2* __restrict__ tok_slot,
    float* __restrict__ out)
{
  int t = blockIdx.x;
  int c8 = threadIdx.x;
  float4 wf = tok_wf[t];
  int2 sl = tok_slot[t];
  u16x8 a  = *((const u16x8*)(eo + (size_t)sl.x * D_DIM) + c8);
  u16x8 b  = *((const u16x8*)(eo + (size_t)sl.y * D_DIM) + c8);
  u16x8 dn = *((const u16x8*)(dense_o + (size_t)t * D_DIM) + c8);
  float* op = out + (size_t)t * D_DIM + c8 * 8;
  #pragma unroll
  for (int j = 0; j < 8; ++j) {
    float mo = wf.x * bf2f(a[j]) + wf.y * bf2f(b[j]);
    op[j] = wf.z * mo + wf.w * bf2f(dn[j]);
  }
}

// ---------------- launch ----------------
extern "C" void kernel_launch(void* const* d_in, const int* in_sizes, int n_in,
                              void* d_out, int out_size, void* d_ws, size_t ws_size,
                              hipStream_t stream)
{
  const float* x   = (const float*)d_in[0];
  const float* Wr  = (const float*)d_in[1];
  const float* br  = (const float*)d_in[2];
  const float* Wg  = (const float*)d_in[3];
  const float* bg  = (const float*)d_in[4];
  const float* W1  = (const float*)d_in[5];
  const float* b1  = (const float*)d_in[6];
  const float* W2  = (const float*)d_in[7];
  const float* b2  = (const float*)d_in[8];
  const float* D1  = (const float*)d_in[9];
  const float* d1b = (const float*)d_in[10];
  const float* D2  = (const float*)d_in[11];
  const float* d2b = (const float*)d_in[12];
  float* out = (float*)d_out;

  char* base = (char*)d_ws;
  size_t cur = 0;
  auto alloc = [&](size_t b) -> void* {
    void* p = base + cur; cur = (cur + b + 255) & ~(size_t)255; return p;
  };
  int*    hdr      = (int*)   alloc(256 * sizeof(int));
  int4*   tilemap  = (int4*)  alloc((size_t)RT_MAX * sizeof(int4));
  int4*   tok_sel  = (int4*)  alloc((size_t)T_TOK * sizeof(int4));
  float4* tok_wf   = (float4*)alloc((size_t)T_TOK * sizeof(float4));
  int2*   tok_slot = (int2*)  alloc((size_t)T_TOK * sizeof(int2));
  int*    perm     = (int*)   alloc((size_t)SLOT_MAX * sizeof(int));
  u16*    xb       = (u16*)   alloc((size_t)T_TOK * D_DIM * 2);
  u16*    xg       = (u16*)   alloc((size_t)SLOT_MAX * D_DIM * 2);
  u16*    W1bt     = (u16*)   alloc((size_t)E_NUM * D_DIM * FF_DIM * 2);
  u16*    W2bt     = (u16*)   alloc((size_t)E_NUM * D_DIM * FF_DIM * 2);
  u16*    D1bt     = (u16*)   alloc((size_t)D_DIM * FF_DIM * 2);
  u16*    D2bt     = (u16*)   alloc((size_t)D_DIM * FF_DIM * 2);
  u16*    h_moe    = (u16*)   alloc((size_t)SLOT_MAX * FF_DIM * 2);
  u16*    h_dense  = (u16*)   alloc((size_t)T_TOK * FF_DIM * 2);
  u16*    eo       = (u16*)   alloc((size_t)SLOT_MAX * D_DIM * 2);
  u16*    dense_o  = (u16*)   alloc((size_t)T_TOK * D_DIM * 2);
  (void)in_sizes; (void)n_in; (void)out_size; (void)ws_size; // needs ~475 MB of ws

  k_init   <<<1, 64, 0, stream>>>(hdr);
  k_route  <<<T_TOK / 4, 256, 0, stream>>>(x, Wr, br, Wg, bg, hdr, tok_sel, tok_wf);
  k_offsets<<<1, 256, 0, stream>>>(hdr, tilemap, perm);
  k_scatter<<<T_TOK / 256, 256, 0, stream>>>(tok_sel, hdr, perm, tok_slot);
  k_cast   <<<(T_TOK * D_DIM / 8) / 256, 256, 0, stream>>>(x, xb, T_TOK * D_DIM / 8);
  k_gather <<<SLOT_MAX / 2, 256, 0, stream>>>(xb, perm, hdr, xg);
  k_tcast  <<<dim3(FF_DIM / 64, D_DIM / 64, E_NUM), 256, 0, stream>>>(W1, W1bt, D_DIM, FF_DIM);
  k_tcast  <<<dim3(D_DIM / 64, FF_DIM / 64, E_NUM), 256, 0, stream>>>(W2, W2bt, FF_DIM, D_DIM);
  k_tcast  <<<dim3(FF_DIM / 64, D_DIM / 64, 1), 256, 0, stream>>>(D1, D1bt, D_DIM, FF_DIM);
  k_tcast  <<<dim3(D_DIM / 64, FF_DIM / 64, 1), 256, 0, stream>>>(D2, D2bt, FF_DIM, D_DIM);

  // GEMM1: [slots|tokens] x W1 -> relu -> h   (BN=256: grid 16x104, K=1024)
  k_gemm_ring<256, 1><<<dim3(FF_DIM / 256, RT_MAX), 512, 0, stream>>>(
      xg, xb, W1bt, D1bt, b1, d1b, h_moe, h_dense, hdr, tilemap,
      D_DIM, FF_DIM, (long)D_DIM * FF_DIM, FF_DIM, 4);
  // GEMM2: h x W2 -> eo   (BN=128: grid 8x104, K=4096; 3.25 rounds vs 1.6 at BN=256)
  k_gemm_ring<128, 0><<<dim3(D_DIM / 128, RT_MAX), 512, 0, stream>>>(
      h_moe, h_dense, W2bt, D2bt, b2, d2b, eo, dense_o, hdr, tilemap,
      FF_DIM, D_DIM, (long)D_DIM * FF_DIM, D_DIM, 3);

  k_combine<<<T_TOK, 128, 0, stream>>>(eo, dense_o, tok_wf, tok_slot, out);
}

// Round 4
// 795.957 us; speedup vs baseline: 1.3499x; 1.2754x over previous
//
#include <hip/hip_runtime.h>
#include <stdint.h>

// ---------------- problem constants ----------------
#define T_TOK   8192          // B*S
#define D_DIM   1024
#define FF_DIM  4096
#define E_NUM   8
#define SLOT_MAX 18432        // 16384 + 8*256 (worst-case 256-padded slots)
#define RT_MAX  104           // 72 moe row-tiles + 32 dense row-tiles (256-row tiles)

typedef unsigned int   u32;
typedef unsigned short u16;
typedef __attribute__((ext_vector_type(4))) float  f32x4;
typedef __attribute__((ext_vector_type(4))) float  f4;
typedef __attribute__((ext_vector_type(8))) short  bf16x8;   // 8 bf16 = 4 VGPR
typedef __attribute__((ext_vector_type(8))) unsigned short u16x8;

__device__ __forceinline__ u16 f2bf(float f) {              // RNE f32->bf16
  u32 u = __builtin_bit_cast(u32, f);
  return (u16)((u + 0x7fffu + ((u >> 16) & 1u)) >> 16);
}
__device__ __forceinline__ float bf2f(u16 h) {
  u32 u = ((u32)h) << 16; return __builtin_bit_cast(float, u);
}

typedef const __attribute__((address_space(1))) u32* gp1_t;
typedef __attribute__((address_space(3))) u32*       lp3_t;
__device__ __forceinline__ void gload16(const u16* g, u16* l) {
  // async global->LDS, 16B/lane, LDS dest = wave-uniform base + lane*16 (linear)
  __builtin_amdgcn_global_load_lds((gp1_t)(const void*)g, (lp3_t)l, 16, 0, 0);
}

// ---------------- K0: zero header ----------------
__global__ void k_init(int* hdr) { if (threadIdx.x < 64) hdr[threadIdx.x] = 0; }

// ---------------- K1: router + gate (wave per token) ----------------
__global__ __launch_bounds__(256) void k_route(
    const float* __restrict__ x, const float* __restrict__ Wr, const float* __restrict__ br,
    const float* __restrict__ Wg, const float* __restrict__ bg,
    int* __restrict__ hdr, int4* __restrict__ tok_sel, float4* __restrict__ tok_wf)
{
  int w = threadIdx.x >> 6, l = threadIdx.x & 63;
  int t = blockIdx.x * 4 + w;
  const float* xt = x + (size_t)t * D_DIM;
  float p[10];
  #pragma unroll
  for (int i = 0; i < 10; ++i) p[i] = 0.f;
  for (int j = 0; j < D_DIM / 64; ++j) {
    int d = j * 64 + l;
    float xv = xt[d];
    p[0] += xv * Wr[d * 2 + 0];
    p[1] += xv * Wr[d * 2 + 1];
    f4 g0 = *(const f4*)&Wg[d * 8];
    f4 g1 = *(const f4*)&Wg[d * 8 + 4];
    p[2] += xv * g0[0]; p[3] += xv * g0[1]; p[4] += xv * g0[2]; p[5] += xv * g0[3];
    p[6] += xv * g1[0]; p[7] += xv * g1[1]; p[8] += xv * g1[2]; p[9] += xv * g1[3];
  }
  #pragma unroll
  for (int off = 32; off; off >>= 1) {
    #pragma unroll
    for (int i = 0; i < 10; ++i) p[i] += __shfl_xor(p[i], off, 64);
  }
  if (l == 0) {
    float a0 = p[0] + br[0], a1 = p[1] + br[1];
    float m  = fmaxf(a0, a1);
    float e0 = __expf(a0 - m), e1 = __expf(a1 - m);
    float rs = 1.f / (e0 + e1);
    float rp0 = e0 * rs, rp1 = e1 * rs;
    float g[E_NUM]; float gm = -1e30f;
    #pragma unroll
    for (int e = 0; e < E_NUM; ++e) { g[e] = p[2 + e] + bg[e]; gm = fmaxf(gm, g[e]); }
    int i0 = 0;
    #pragma unroll
    for (int e = 1; e < E_NUM; ++e) if (g[e] > g[i0]) i0 = e;      // earliest max tiebreak
    int i1 = (i0 == 0) ? 1 : 0;
    #pragma unroll
    for (int e = 0; e < E_NUM; ++e) if (e != i0 && g[e] > g[i1]) i1 = e;
    float x0 = __expf(g[i0] - gm), x1 = __expf(g[i1] - gm);
    float s = 1.f / (x0 + x1);
    int r0 = atomicAdd(&hdr[i0], 1);
    int r1 = atomicAdd(&hdr[i1], 1);
    tok_sel[t] = make_int4(i0, r0, i1, r1);
    tok_wf[t]  = make_float4(x0 * s, x1 * s, rp0, rp1);
  }
}

// ---------------- K2: padded offsets + tile map + perm=-1 ----------------
__global__ __launch_bounds__(256) void k_offsets(int* __restrict__ hdr,
                                                 int4* __restrict__ tilemap,
                                                 int* __restrict__ perm)
{
  __shared__ int soff[E_NUM + 1];
  int tid = threadIdx.x;
  if (tid == 0) {
    int acc = 0;
    for (int e = 0; e < E_NUM; ++e) {
      soff[e] = acc; hdr[8 + e] = acc;
      acc += (hdr[e] + 255) & ~255;                // pad each expert to 256
    }
    soff[E_NUM] = acc;
    hdr[16] = acc;                                 // nslots_padded
    hdr[17] = acc >> 8;                            // moe row-tiles (256-row)
    hdr[18] = (acc >> 8) + T_TOK / 256;            // total row-tiles
  }
  __syncthreads();
  int nmoe = soff[E_NUM] >> 8;
  for (int rt = tid; rt < RT_MAX; rt += 256) {
    int4 ent;
    if (rt < nmoe) {
      int row0 = rt * 256;
      int e = 0;
      while (e < E_NUM - 1 && row0 >= soff[e + 1]) ++e;
      ent = make_int4(0, row0, e, 0);
    } else if (rt < nmoe + T_TOK / 256) {
      ent = make_int4(1, (rt - nmoe) * 256, -1, 0);
    } else {
      ent = make_int4(-1, 0, 0, 0);
    }
    tilemap[rt] = ent;
  }
  for (int s = tid; s < SLOT_MAX; s += 256) perm[s] = -1;
}

// ---------------- K3: scatter token -> slots ----------------
__global__ void k_scatter(const int4* __restrict__ tok_sel, const int* __restrict__ hdr,
                          int* __restrict__ perm, int2* __restrict__ tok_slot)
{
  int t = blockIdx.x * 256 + threadIdx.x;
  if (t >= T_TOK) return;
  int4 s = tok_sel[t];
  int s0 = hdr[8 + s.x] + s.y;
  int s1 = hdr[8 + s.z] + s.w;
  perm[s0] = t; perm[s1] = t;
  tok_slot[t] = make_int2(s0, s1);
}

// ---------------- K4: cast x -> bf16 ----------------
__global__ void k_cast(const float* __restrict__ x, u16* __restrict__ xb, int n8) {
  int i = blockIdx.x * 256 + threadIdx.x;
  if (i >= n8) return;
  const f4* src = (const f4*)x + (size_t)i * 2;
  f4 a = src[0], b = src[1];
  u16x8 o;
  o[0]=f2bf(a[0]); o[1]=f2bf(a[1]); o[2]=f2bf(a[2]); o[3]=f2bf(a[3]);
  o[4]=f2bf(b[0]); o[5]=f2bf(b[1]); o[6]=f2bf(b[2]); o[7]=f2bf(b[3]);
  ((u16x8*)xb)[i] = o;
}

// ---------------- K5: gather x rows into slot order ----------------
__global__ __launch_bounds__(256) void k_gather(const u16* __restrict__ xb,
                                                const int* __restrict__ perm,
                                                const int* __restrict__ hdr,
                                                u16* __restrict__ xg)
{
  int nslots = hdr[16];
  int row = blockIdx.x * 2 + (threadIdx.x >> 7);
  if (row >= nslots) return;
  int lane = threadIdx.x & 127;
  int t = perm[row];
  u16x8* dst = (u16x8*)(xg + (size_t)row * D_DIM) + lane;
  if (t < 0) { u16x8 z = {0,0,0,0,0,0,0,0}; *dst = z; }
  else       { *dst = *((const u16x8*)(xb + (size_t)t * D_DIM) + lane); }
}

// ---------------- K6: cast+transpose f32 [R,C] -> bf16 [C,R] ----------------
__global__ __launch_bounds__(256) void k_tcast(const float* __restrict__ src,
                                               u16* __restrict__ dst, int R, int C)
{
  const float* s = src + (size_t)blockIdx.z * R * C;
  u16* d = dst + (size_t)blockIdx.z * R * C;
  __shared__ float tile[64][65];
  int tr = blockIdx.y, tc = blockIdx.x;
  int t = threadIdx.x;
  #pragma unroll
  for (int p = 0; p < 4; ++p) {
    int r = p * 16 + (t >> 4);
    int c4 = (t & 15) * 4;
    f4 v = *(const f4*)&s[(size_t)(tr * 64 + r) * C + tc * 64 + c4];
    tile[r][c4+0] = v[0]; tile[r][c4+1] = v[1]; tile[r][c4+2] = v[2]; tile[r][c4+3] = v[3];
  }
  __syncthreads();
  #pragma unroll
  for (int q = 0; q < 2; ++q) {
    int oc = q * 32 + (t >> 3);
    int r8 = (t & 7) * 8;
    u16x8 o;
    #pragma unroll
    for (int j = 0; j < 8; ++j) o[j] = f2bf(tile[r8 + j][oc]);
    *(u16x8*)&d[(size_t)(tc * 64 + oc) * R + tr * 64 + r8] = o;
  }
}

// ---------------- K7/K8: grouped GEMM, m201-style 8-phase, BM=BN=256, BK=64 ----
// 8 waves (2M x 4N), per-wave 128x64 out. LDS 128KB: A = 2dbuf x 2half x 128x64,
// B same (u16 idx: A region (b*2+h)*8192, B +32768). Reads XOR-swizzled
// (byte ^= (row&7)<<4) realized via pre-swizzled STAGE SOURCE (rule #21).
// Per K-tile, 4 phases (quadrants (0,0),(0,1),(1,1),(1,0)); ds_reads 12/4/8/0;
// stages: A-h1(t+1)@P1, B-h0(t+2)@P3, B-h1(t+2)+A-h0(t+2)@P4; ONE vmcnt(6)
// (= 3 half-tiles in flight) at P4 end BEFORE the closing barrier.
// Region-safety ledger: each region's last ds_read drains at the reader's own
// lgkmcnt(0) >=1 barrier before that region is re-staged; each tile's halves
// are vmcnt-certified by all waves before the barrier preceding first read.
#define LGKM0() { asm volatile("s_waitcnt lgkmcnt(0)" ::: "memory"); \
                  __builtin_amdgcn_sched_barrier(0); }
#define BAR()   __builtin_amdgcn_s_barrier()

template <int RELU>
__global__ __launch_bounds__(512, 2) void k_gemm8p(
    const u16* __restrict__ Amoe, const u16* __restrict__ Aden,
    const u16* __restrict__ Bexp, const u16* __restrict__ Bden,
    const float* __restrict__ biasexp, const float* __restrict__ biasden,
    u16* __restrict__ Omoe, u16* __restrict__ Oden,
    const int* __restrict__ hdr, const int4* __restrict__ tilemap,
    int K, int N, long bexp_stride, int biasexp_stride, int lg2gx)
{
  // bijective XCD-aware swizzle (nwg % 8 == 0 for both launches)
  int gx  = 1 << lg2gx;
  int nwg = gx * gridDim.y;
  int lin = blockIdx.y * gx + blockIdx.x;
  int sw  = (lin & 7) * (nwg >> 3) + (lin >> 3);
  int ct  = sw & (gx - 1);
  int rt  = sw >> lg2gx;
  if (rt >= hdr[18]) return;

  int4 ent = tilemap[rt];
  const u16* A; const u16* B; const float* bias; u16* O;
  if (ent.x == 1) { A = Aden; B = Bden; bias = biasden; O = Oden; }
  else {
    A = Amoe; B = Bexp + (size_t)ent.z * bexp_stride;
    bias = biasexp + (size_t)ent.z * biasexp_stride;
    O = Omoe;
  }
  const int row0 = ent.y;

  __shared__ __align__(16) u16 lds[65536];     // 128KB

  const int tid = threadIdx.x;
  const int wid = tid >> 6, l = tid & 63;
  const int wm = wid >> 2, wn = wid & 3;

  // --- staging source (pre-swizzled k within each row; LDS dest linear) ---
  const int skel = ((l & 7) ^ (l >> 3)) * 8;            // swizzled k-elem in [0,64)
  const u16* aStage = A + (size_t)(row0     + wid * 8 + (l >> 3)) * K + skel;
  const u16* bStage = B + (size_t)(ct * 256 + wid * 8 + (l >> 3)) * K + skel;

  // --- frag-read constants ---
  const int fr = l & 15, fq = l >> 4;
  const int fx = (l & 7) << 4;                           // row&7 == l&7 for frag rows
  const int cs0 = (fq * 16) ^ fx;                        // k-slice 0 byte col
  const int cs1 = (64 + fq * 16) ^ fx;                   // k-slice 1 byte col
  const char* ldsc = (const char*)lds;

  // stage: A half h of K-tile tt into dbuf bb (2 x gload16 per thread)
  auto STAGE_A = [&](int tt, int h, int bb) {
    const u16* src = aStage + (size_t)(h * 128) * K + (size_t)tt * 64;
    u16* dst = &lds[(bb * 2 + h) * 8192 + wid * 512];
    gload16(src, dst);
    gload16(src + (size_t)64 * K, dst + 4096);
  };
  auto STAGE_B = [&](int tt, int h, int bb) {
    const u16* src = bStage + (size_t)(h * 128) * K + (size_t)tt * 64;
    u16* dst = &lds[32768 + (bb * 2 + h) * 8192 + wid * 512];
    gload16(src, dst);
    gload16(src + (size_t)64 * K, dst + 4096);
  };

  f32x4 acc[8][4];
  #pragma unroll
  for (int m = 0; m < 8; ++m)
    #pragma unroll
    for (int n = 0; n < 4; ++n) acc[m][n] = (f32x4){0.f, 0.f, 0.f, 0.f};

  const int NK = K >> 6;                                 // 16 or 64

  // prologue: 7 half-tiles; ledger at loop entry = [B-h0(1), B-h1(1), A-h0(1)]
  STAGE_B(0, 0, 0); STAGE_B(0, 1, 0); STAGE_A(0, 0, 0); STAGE_A(0, 1, 0);
  STAGE_B(1, 0, 1); STAGE_B(1, 1, 1); STAGE_A(1, 0, 1);
  asm volatile("s_waitcnt vmcnt(6)" ::: "memory");       // tile 0 fully landed
  BAR();

  bf16x8 a0[4][2], a1[4][2], b0[2][2], b1[2][2];

  for (int t = 0; t < NK; ++t) {
    const int b = t & 1;
    const char* Areg = ldsc + (size_t)(b * 2 + wm) * 16384;
    const char* Breg = ldsc + 65536 + (size_t)(b * 2 + (wn >> 1)) * 16384;
    const int brow = (wn & 1) * 64;

    // ---- P1: quadrant (mh0, nh0); reads A-mh0(8) + B-nh0(4); stage A-h1(t+1)
    #pragma unroll
    for (int j = 0; j < 4; ++j) {
      a0[j][0] = *(const bf16x8*)(Areg + (j * 16 + fr) * 128 + cs0);
      a0[j][1] = *(const bf16x8*)(Areg + (j * 16 + fr) * 128 + cs1);
    }
    #pragma unroll
    for (int i = 0; i < 2; ++i) {
      b0[i][0] = *(const bf16x8*)(Breg + (brow + i * 16 + fr) * 128 + cs0);
      b0[i][1] = *(const bf16x8*)(Breg + (brow + i * 16 + fr) * 128 + cs1);
    }
    if (t + 1 < NK) STAGE_A(t + 1, 1, b ^ 1);
    BAR(); LGKM0();
    __builtin_amdgcn_s_setprio(1);
    #pragma unroll
    for (int j = 0; j < 4; ++j)
      #pragma unroll
      for (int i = 0; i < 2; ++i) {
        acc[j][i] = __builtin_amdgcn_mfma_f32_16x16x32_bf16(a0[j][0], b0[i][0], acc[j][i], 0, 0, 0);
        acc[j][i] = __builtin_amdgcn_mfma_f32_16x16x32_bf16(a0[j][1], b0[i][1], acc[j][i], 0, 0, 0);
      }
    __builtin_amdgcn_s_setprio(0);
    BAR();

    // ---- P2: quadrant (mh0, nh1); reads B-nh1(4)
    #pragma unroll
    for (int i = 0; i < 2; ++i) {
      b1[i][0] = *(const bf16x8*)(Breg + (brow + 32 + i * 16 + fr) * 128 + cs0);
      b1[i][1] = *(const bf16x8*)(Breg + (brow + 32 + i * 16 + fr) * 128 + cs1);
    }
    BAR(); LGKM0();
    __builtin_amdgcn_s_setprio(1);
    #pragma unroll
    for (int j = 0; j < 4; ++j)
      #pragma unroll
      for (int i = 0; i < 2; ++i) {
        acc[j][2 + i] = __builtin_amdgcn_mfma_f32_16x16x32_bf16(a0[j][0], b1[i][0], acc[j][2 + i], 0, 0, 0);
        acc[j][2 + i] = __builtin_amdgcn_mfma_f32_16x16x32_bf16(a0[j][1], b1[i][1], acc[j][2 + i], 0, 0, 0);
      }
    __builtin_amdgcn_s_setprio(0);
    BAR();

    // ---- P3: quadrant (mh1, nh1); reads A-mh1(8); stage B-h0(t+2)
    #pragma unroll
    for (int j = 0; j < 4; ++j) {
      a1[j][0] = *(const bf16x8*)(Areg + (64 + j * 16 + fr) * 128 + cs0);
      a1[j][1] = *(const bf16x8*)(Areg + (64 + j * 16 + fr) * 128 + cs1);
    }
    if (t + 2 < NK) STAGE_B(t + 2, 0, b);
    BAR(); LGKM0();
    __builtin_amdgcn_s_setprio(1);
    #pragma unroll
    for (int j = 0; j < 4; ++j)
      #pragma unroll
      for (int i = 0; i < 2; ++i) {
        acc[4 + j][2 + i] = __builtin_amdgcn_mfma_f32_16x16x32_bf16(a1[j][0], b1[i][0], acc[4 + j][2 + i], 0, 0, 0);
        acc[4 + j][2 + i] = __builtin_amdgcn_mfma_f32_16x16x32_bf16(a1[j][1], b1[i][1], acc[4 + j][2 + i], 0, 0, 0);
      }
    __builtin_amdgcn_s_setprio(0);
    BAR();

    // ---- P4: quadrant (mh1, nh0); no reads; stage B-h1(t+2)+A-h0(t+2); vmcnt
    if (t + 2 < NK) { STAGE_B(t + 2, 1, b); STAGE_A(t + 2, 0, b); }
    BAR();
    __builtin_amdgcn_s_setprio(1);
    #pragma unroll
    for (int j = 0; j < 4; ++j)
      #pragma unroll
      for (int i = 0; i < 2; ++i) {
        acc[4 + j][i] = __builtin_amdgcn_mfma_f32_16x16x32_bf16(a1[j][0], b0[i][0], acc[4 + j][i], 0, 0, 0);
        acc[4 + j][i] = __builtin_amdgcn_mfma_f32_16x16x32_bf16(a1[j][1], b0[i][1], acc[4 + j][i], 0, 0, 0);
      }
    __builtin_amdgcn_s_setprio(0);
    if (t < NK - 2) { asm volatile("s_waitcnt vmcnt(6)" ::: "memory"); }
    else            { asm volatile("s_waitcnt vmcnt(0)" ::: "memory"); }
    BAR();
    __builtin_amdgcn_sched_barrier(0);
  }

  // ---- epilogue: per-wave LDS-bounce transpose -> coalesced u16x8 stores ----
  __syncthreads();
  float bv[4];
  #pragma unroll
  for (int ni = 0; ni < 4; ++ni) bv[ni] = bias[ct * 256 + wn * 64 + ni * 16 + fr];
  float* ep = (float*)((char*)lds + wid * 4096);
  const int row16 = l >> 2, cg = l & 3;
  #pragma unroll
  for (int mi = 0; mi < 8; ++mi) {
    #pragma unroll
    for (int ni = 0; ni < 4; ++ni) {
      f32x4 v = acc[mi][ni];
      #pragma unroll
      for (int j = 0; j < 4; ++j) {
        float f = v[j] + bv[ni];
        if (RELU) f = fmaxf(f, 0.f);
        ep[(fq * 4 + j) * 64 + ni * 16 + fr] = f;   // wave-private 4KB
      }
    }
    #pragma unroll
    for (int p = 0; p < 2; ++p) {
      f4 r0 = *(f4*)&ep[row16 * 64 + (cg + p * 4) * 8];
      f4 r1 = *(f4*)&ep[row16 * 64 + (cg + p * 4) * 8 + 4];
      u16x8 o;
      o[0]=f2bf(r0[0]); o[1]=f2bf(r0[1]); o[2]=f2bf(r0[2]); o[3]=f2bf(r0[3]);
      o[4]=f2bf(r1[0]); o[5]=f2bf(r1[1]); o[6]=f2bf(r1[2]); o[7]=f2bf(r1[3]);
      int rr = row0 + wm * 128 + mi * 16 + row16;
      int cc = ct * 256 + wn * 64 + (cg + p * 4) * 8;
      *(u16x8*)&O[(size_t)rr * N + cc] = o;
    }
  }
}

// ---------------- K9: combine ----------------
__global__ __launch_bounds__(128) void k_combine(
    const u16* __restrict__ eo, const u16* __restrict__ dense_o,
    const float4* __restrict__ tok_wf, const int2* __restrict__ tok_slot,
    float* __restrict__ out)
{
  int t = blockIdx.x;
  int c8 = threadIdx.x;
  float4 wf = tok_wf[t];
  int2 sl = tok_slot[t];
  u16x8 a  = *((const u16x8*)(eo + (size_t)sl.x * D_DIM) + c8);
  u16x8 b  = *((const u16x8*)(eo + (size_t)sl.y * D_DIM) + c8);
  u16x8 dn = *((const u16x8*)(dense_o + (size_t)t * D_DIM) + c8);
  float* op = out + (size_t)t * D_DIM + c8 * 8;
  #pragma unroll
  for (int j = 0; j < 8; ++j) {
    float mo = wf.x * bf2f(a[j]) + wf.y * bf2f(b[j]);
    op[j] = wf.z * mo + wf.w * bf2f(dn[j]);
  }
}

// ---------------- launch ----------------
extern "C" void kernel_launch(void* const* d_in, const int* in_sizes, int n_in,
                              void* d_out, int out_size, void* d_ws, size_t ws_size,
                              hipStream_t stream)
{
  const float* x   = (const float*)d_in[0];
  const float* Wr  = (const float*)d_in[1];
  const float* br  = (const float*)d_in[2];
  const float* Wg  = (const float*)d_in[3];
  const float* bg  = (const float*)d_in[4];
  const float* W1  = (const float*)d_in[5];
  const float* b1  = (const float*)d_in[6];
  const float* W2  = (const float*)d_in[7];
  const float* b2  = (const float*)d_in[8];
  const float* D1  = (const float*)d_in[9];
  const float* d1b = (const float*)d_in[10];
  const float* D2  = (const float*)d_in[11];
  const float* d2b = (const float*)d_in[12];
  float* out = (float*)d_out;

  char* base = (char*)d_ws;
  size_t cur = 0;
  auto alloc = [&](size_t b) -> void* {
    void* p = base + cur; cur = (cur + b + 255) & ~(size_t)255; return p;
  };
  int*    hdr      = (int*)   alloc(256 * sizeof(int));
  int4*   tilemap  = (int4*)  alloc((size_t)RT_MAX * sizeof(int4));
  int4*   tok_sel  = (int4*)  alloc((size_t)T_TOK * sizeof(int4));
  float4* tok_wf   = (float4*)alloc((size_t)T_TOK * sizeof(float4));
  int2*   tok_slot = (int2*)  alloc((size_t)T_TOK * sizeof(int2));
  int*    perm     = (int*)   alloc((size_t)SLOT_MAX * sizeof(int));
  u16*    xb       = (u16*)   alloc((size_t)T_TOK * D_DIM * 2);
  u16*    xg       = (u16*)   alloc((size_t)SLOT_MAX * D_DIM * 2);
  u16*    W1bt     = (u16*)   alloc((size_t)E_NUM * D_DIM * FF_DIM * 2);
  u16*    W2bt     = (u16*)   alloc((size_t)E_NUM * D_DIM * FF_DIM * 2);
  u16*    D1bt     = (u16*)   alloc((size_t)D_DIM * FF_DIM * 2);
  u16*    D2bt     = (u16*)   alloc((size_t)D_DIM * FF_DIM * 2);
  u16*    h_moe    = (u16*)   alloc((size_t)SLOT_MAX * FF_DIM * 2);
  u16*    h_dense  = (u16*)   alloc((size_t)T_TOK * FF_DIM * 2);
  u16*    eo       = (u16*)   alloc((size_t)SLOT_MAX * D_DIM * 2);
  u16*    dense_o  = (u16*)   alloc((size_t)T_TOK * D_DIM * 2);
  (void)in_sizes; (void)n_in; (void)out_size; (void)ws_size; // needs ~475 MB of ws

  k_init   <<<1, 64, 0, stream>>>(hdr);
  k_route  <<<T_TOK / 4, 256, 0, stream>>>(x, Wr, br, Wg, bg, hdr, tok_sel, tok_wf);
  k_offsets<<<1, 256, 0, stream>>>(hdr, tilemap, perm);
  k_scatter<<<T_TOK / 256, 256, 0, stream>>>(tok_sel, hdr, perm, tok_slot);
  k_cast   <<<(T_TOK * D_DIM / 8) / 256, 256, 0, stream>>>(x, xb, T_TOK * D_DIM / 8);
  k_gather <<<SLOT_MAX / 2, 256, 0, stream>>>(xb, perm, hdr, xg);
  k_tcast  <<<dim3(FF_DIM / 64, D_DIM / 64, E_NUM), 256, 0, stream>>>(W1, W1bt, D_DIM, FF_DIM);
  k_tcast  <<<dim3(D_DIM / 64, FF_DIM / 64, E_NUM), 256, 0, stream>>>(W2, W2bt, FF_DIM, D_DIM);
  k_tcast  <<<dim3(FF_DIM / 64, D_DIM / 64, 1), 256, 0, stream>>>(D1, D1bt, D_DIM, FF_DIM);
  k_tcast  <<<dim3(D_DIM / 64, FF_DIM / 64, 1), 256, 0, stream>>>(D2, D2bt, FF_DIM, D_DIM);

  // GEMM1: [slots|tokens] x W1 -> relu -> h   (grid 16x104, K=1024, NK=16)
  k_gemm8p<1><<<dim3(FF_DIM / 256, RT_MAX), 512, 0, stream>>>(
      xg, xb, W1bt, D1bt, b1, d1b, h_moe, h_dense, hdr, tilemap,
      D_DIM, FF_DIM, (long)D_DIM * FF_DIM, FF_DIM, 4);
  // GEMM2: h x W2 -> eo   (grid 4x104, K=4096, NK=64)
  k_gemm8p<0><<<dim3(D_DIM / 256, RT_MAX), 512, 0, stream>>>(
      h_moe, h_dense, W2bt, D2bt, b2, d2b, eo, dense_o, hdr, tilemap,
      FF_DIM, D_DIM, (long)D_DIM * FF_DIM, D_DIM, 2);

  k_combine<<<T_TOK, 128, 0, stream>>>(eo, dense_o, tok_wf, tok_slot, out);
}